// Round 10
// baseline (98.233 us; speedup 1.0000x reference)
//
#include <hip/hip_runtime.h>
#include <hip/hip_bf16.h>

// GraphAttentionLayer: N=16, Cin=64, T=512, V=64.
// PERSISTENT blocks (grid=1536, grid-stride over b=n*T+t) with software
// pipeline: next-b x-loads issue after the stage barrier and fly across
// mm1+softmax+mm2. Per-iteration phases are r3's verified 54.6us code:
//   stage(X,Wt from regs) -> bar -> mm1 (+f/g partials) -> bar ->
//   softmax (unnormalized base-2, rows i=4k+w) -> bar -> mm2 + stores -> bar.
// Loop-invariant in regs: W fragments (wtr), a1v/a2v, ml(LDS).

using bf16x8 = __attribute__((ext_vector_type(8))) short;
using f32x4  = __attribute__((ext_vector_type(4))) float;
typedef unsigned long long ull;

constexpr float ALPHA = 0.2f;
constexpr float LOG2E = 1.4426950408889634f;
constexpr int NB   = 8192;   // 16*512
constexpr int GRID = 1536;   // 6 blocks/CU * 256 CU

__device__ __forceinline__ unsigned short f2bf(float f) {
    union { __hip_bfloat16 h; unsigned short s; } u;
    u.h = __float2bfloat16(f);
    return u.s;
}

// prep: Wt[v][u] = bf16(W[u][v]); maskbits[i] bit j = (Asum[i][j]>0)
__global__ void prep_kernel(const float* __restrict__ A,
                            const float* __restrict__ W,
                            unsigned short* __restrict__ Wt,
                            ull* __restrict__ mask) {
    const int tid = threadIdx.x;          // 256
    const int v = tid & 63, qq = tid >> 6;
    #pragma unroll 4
    for (int m = 0; m < 16; ++m) {
        const int u = 16 * qq + m;
        Wt[v * 64 + u] = f2bf(W[u * 64 + v]);
    }
    if (tid < 64) {
        ull m = 0;
        for (int j = 0; j < 64; ++j) {
            float s = A[tid * 64 + j] + A[4096 + tid * 64 + j] + A[8192 + tid * 64 + j];
            if (s > 0.f) m |= (1ull << j);
        }
        mask[tid] = m;
    }
}

__global__ __launch_bounds__(256, 6) void gat_kernel(
    const float* __restrict__ x,                 // (16,64,512,64) f32
    const float* __restrict__ a,                 // (128,)
    const unsigned short* __restrict__ Wt,       // (64,64) bf16, [v][u]
    const ull* __restrict__ maskbits,            // (64,)
    float* __restrict__ out)                     // (16,64,512,64) f32
{
    // stride-72 ushort rows (144B): row-parallel b128 access <=2-way on banks.
    // LDS = 9216 + 9216 + 1024 + 1024 + 512 = 20992 B.
    __shared__ unsigned short XbYb[64 * 72];  // X (mm1 A) then Y (mm2 A)
    __shared__ unsigned short WtPb[64 * 72];  // Wt (mm1 B^T) then P (mm2 B^T)
    __shared__ float fpart[4][64];
    __shared__ float gpart[4][64];
    __shared__ ull ml[64];

    const int tid = threadIdx.x;
    const int w = tid >> 6, lane = tid & 63;
    const int fr = lane & 15, hi = lane >> 4, fk = hi * 8;
    const int c = tid >> 2, q = tid & 3;

    if (tid < 64) ml[tid] = maskbits[tid];
    const float4 a1v = *(const float4*)&a[16 * w + 4 * hi];
    const float4 a2v = *(const float4*)&a[64 + 16 * w + 4 * hi];

    // W held in regs for the whole kernel; re-staged to LDS each iter
    // (WtPb is overwritten by P every iteration).
    const int wr = tid >> 3;            // 0..31
    const int wc = (tid & 7) * 8;       // 0..56
    bf16x8 wtr0 = *(const bf16x8*)&Wt[wr * 64 + wc];
    bf16x8 wtr1 = *(const bf16x8*)&Wt[(wr + 32) * 64 + wc];

    int b = blockIdx.x;
    const size_t xoff = (size_t)c * 32768 + q * 16;
    {   // prologue load for first b
        const float* xp = x + (size_t)(b >> 9) * 2097152 + (size_t)(b & 511) * 64 + xoff;
        float4 xv0 = ((const float4*)xp)[0];
        float4 xv1 = ((const float4*)xp)[1];
        float4 xv2 = ((const float4*)xp)[2];
        float4 xv3 = ((const float4*)xp)[3];

        while (true) {
            // ---- stage X (regs -> bf16 -> LDS) + Wt (regs -> LDS) ----
            {
                union { bf16x8 v; unsigned short s[8]; } u0, u1;
                u0.s[0]=f2bf(xv0.x); u0.s[1]=f2bf(xv0.y); u0.s[2]=f2bf(xv0.z); u0.s[3]=f2bf(xv0.w);
                u0.s[4]=f2bf(xv1.x); u0.s[5]=f2bf(xv1.y); u0.s[6]=f2bf(xv1.z); u0.s[7]=f2bf(xv1.w);
                u1.s[0]=f2bf(xv2.x); u1.s[1]=f2bf(xv2.y); u1.s[2]=f2bf(xv2.z); u1.s[3]=f2bf(xv2.w);
                u1.s[4]=f2bf(xv3.x); u1.s[5]=f2bf(xv3.y); u1.s[6]=f2bf(xv3.z); u1.s[7]=f2bf(xv3.w);
                *(bf16x8*)&XbYb[c * 72 + q * 16]     = u0.v;
                *(bf16x8*)&XbYb[c * 72 + q * 16 + 8] = u1.v;
                *(bf16x8*)&WtPb[wr * 72 + wc]        = wtr0;
                *(bf16x8*)&WtPb[(wr + 32) * 72 + wc] = wtr1;
            }
            __syncthreads();

            // ---- issue next-b x loads (fly across mm1+softmax+mm2) ----
            const int bn = b + GRID;
            const bool last = (bn >= NB);
            {
                const int bl = last ? b : bn;   // clamped refetch is L3-hot
                const float* xpn = x + (size_t)(bl >> 9) * 2097152
                                     + (size_t)(bl & 511) * 64 + xoff;
                xv0 = ((const float4*)xpn)[0];
                xv1 = ((const float4*)xpn)[1];
                xv2 = ((const float4*)xpn)[2];
                xv3 = ((const float4*)xpn)[3];
            }

            // ---- mm1: Y = X @ W; wave w owns rows 16w..16w+15 ----
            {
                f32x4 acc[4] = {{0,0,0,0},{0,0,0,0},{0,0,0,0},{0,0,0,0}};
                #pragma unroll
                for (int kc = 0; kc < 2; ++kc) {
                    bf16x8 af = *(const bf16x8*)&XbYb[(16 * w + fr) * 72 + 32 * kc + fk];
                    #pragma unroll
                    for (int cb = 0; cb < 4; ++cb) {
                        bf16x8 bfr = *(const bf16x8*)&WtPb[(16 * cb + fr) * 72 + 32 * kc + fk];
                        acc[cb] = __builtin_amdgcn_mfma_f32_16x16x32_bf16(af, bfr, acc[cb], 0, 0, 0);
                    }
                }
                // epilogue: Y -> LDS bf16 (own rows), f/g partials (log2e-scaled)
                #pragma unroll
                for (int cb = 0; cb < 4; ++cb) {
                    #pragma unroll
                    for (int r = 0; r < 4; ++r)
                        XbYb[(16 * w + 4 * hi + r) * 72 + 16 * cb + fr] = f2bf(acc[cb][r]);
                    float F = acc[cb][0]*a1v.x + acc[cb][1]*a1v.y + acc[cb][2]*a1v.z + acc[cb][3]*a1v.w;
                    float G = acc[cb][0]*a2v.x + acc[cb][1]*a2v.y + acc[cb][2]*a2v.z + acc[cb][3]*a2v.w;
                    F += __shfl_xor(F, 16, 64); F += __shfl_xor(F, 32, 64);
                    G += __shfl_xor(G, 16, 64); G += __shfl_xor(G, 32, 64);
                    if (lane < 16) {
                        fpart[w][16 * cb + lane] = F * LOG2E;
                        gpart[w][16 * cb + lane] = G * LOG2E;
                    }
                }
            }
            __syncthreads();

            // ---- softmax rows i = 4k+w (unnormalized, base-2) ----
            {
                const float gj = (gpart[0][lane] + gpart[1][lane])
                               + (gpart[2][lane] + gpart[3][lane]);
                #pragma unroll 4
                for (int k = 0; k < 16; ++k) {
                    const int i = 4 * k + w;
                    const ull mi = ml[i];
                    const float fi = (fpart[0][i] + fpart[1][i])
                                   + (fpart[2][i] + fpart[3][i]);
                    const float s0 = fi + gj;
                    const float e = fmaxf(s0, ALPHA * s0);   // lrelu
                    const float p = (mi == 0ull) ? 1.0f
                                  : (((mi >> lane) & 1ull) ? exp2f(e) : 0.0f);
                    WtPb[i * 72 + lane] = f2bf(p);
                }
            }
            __syncthreads();

            // ---- mm2: out[c,v] = (sum_j Y[c,j]P[v,j]) * rcp(S_v) ----
            {
                union { bf16x8 v; unsigned short s[8]; } ones;
                #pragma unroll
                for (int j = 0; j < 8; ++j) ones.s[j] = 0x3f80;   // bf16 1.0
                bf16x8 pb0 = *(const bf16x8*)&WtPb[(16 * w + fr) * 72 + fk];
                bf16x8 pb1 = *(const bf16x8*)&WtPb[(16 * w + fr) * 72 + 32 + fk];
                f32x4 accS = {0, 0, 0, 0};
                accS = __builtin_amdgcn_mfma_f32_16x16x32_bf16(ones.v, pb0, accS, 0, 0, 0);
                accS = __builtin_amdgcn_mfma_f32_16x16x32_bf16(ones.v, pb1, accS, 0, 0, 0);
                f32x4 acc2[4] = {{0,0,0,0},{0,0,0,0},{0,0,0,0},{0,0,0,0}};
                #pragma unroll
                for (int rb = 0; rb < 4; ++rb) {
                    bf16x8 y0 = *(const bf16x8*)&XbYb[(16 * rb + fr) * 72 + fk];
                    bf16x8 y1 = *(const bf16x8*)&XbYb[(16 * rb + fr) * 72 + 32 + fk];
                    acc2[rb] = __builtin_amdgcn_mfma_f32_16x16x32_bf16(y0, pb0, acc2[rb], 0, 0, 0);
                    acc2[rb] = __builtin_amdgcn_mfma_f32_16x16x32_bf16(y1, pb1, acc2[rb], 0, 0, 0);
                }
                const float rs = __builtin_amdgcn_rcpf(accS[0]);   // S_v, v=16w+fr
                float* op = out + (size_t)(b >> 9) * 2097152 + (size_t)(b & 511) * 64
                                + 16 * w + fr;
                #pragma unroll
                for (int rb = 0; rb < 4; ++rb)
                    #pragma unroll
                    for (int r = 0; r < 4; ++r)
                        op[(size_t)(16 * rb + 4 * hi + r) * 32768] = acc2[rb][r] * rs;
            }
            __syncthreads();   // WAR: protect XbYb/WtPb before next stage

            if (last) break;
            b = bn;
        }
    }
}

extern "C" void kernel_launch(void* const* d_in, const int* in_sizes, int n_in,
                              void* d_out, int out_size, void* d_ws, size_t ws_size,
                              hipStream_t stream) {
    const float* x = (const float*)d_in[0];
    const float* A = (const float*)d_in[1];
    const float* W = (const float*)d_in[2];
    const float* a = (const float*)d_in[3];
    float* out = (float*)d_out;
    unsigned short* Wt = (unsigned short*)d_ws;     // 8192 B
    ull* mask = (ull*)((char*)d_ws + 8192);         // 512 B

    prep_kernel<<<1, 256, 0, stream>>>(A, W, Wt, mask);
    gat_kernel<<<GRID, 256, 0, stream>>>(x, a, Wt, mask, out);
}

// Round 11
// 54.243 us; speedup vs baseline: 1.8110x; 1.8110x over previous
//
#include <hip/hip_runtime.h>
#include <hip/hip_bf16.h>

// GraphAttentionLayer: N=16, Cin=64, T=512, V=64. Per b = n*T+t.
// r3-verbatim structure (54.6us best): stage(X,Wt) -> bar -> mm1 (+f/g
// partials in epilogue) -> bar -> softmax rows i=4k+w (unnormalized) -> bar
// -> mm2 (rowsum via ones-MFMA). Only deltas vs r3: (1) prep widened to 256
// threads (was 1 wave, ~2-4us serial), (2) Wt pre-converted bf16 in ws and
// staged with 2 b128 copies (was 16KB f32 read + 16 f2bf + 16 scalar writes).

using bf16x8 = __attribute__((ext_vector_type(8))) short;
using f32x4  = __attribute__((ext_vector_type(4))) float;
typedef unsigned long long ull;

constexpr float ALPHA = 0.2f;

__device__ __forceinline__ unsigned short f2bf(float f) {
    union { __hip_bfloat16 h; unsigned short s; } u;
    u.h = __float2bfloat16(f);
    return u.s;
}

// prep (1 block, 256 thr): Wt[v][u]=bf16(W[u][v]); maskbits[i] bit j = Asum>0
__global__ void prep_kernel(const float* __restrict__ A,
                            const float* __restrict__ W,
                            unsigned short* __restrict__ Wt,
                            ull* __restrict__ mask) {
    __shared__ unsigned short part[64][4];
    const int tid = threadIdx.x;
    // Wt: v = tid&63, q = tid>>6 covers u = 16q..16q+15
    {
        const int v = tid & 63, q = tid >> 6;
        #pragma unroll 4
        for (int m = 0; m < 16; ++m) {
            const int u = 16 * q + m;
            Wt[v * 64 + u] = f2bf(W[u * 64 + v]);
        }
    }
    // mask: 4 threads per row i, 16 cols each via float4 loads
    {
        const int i = tid >> 2, q = tid & 3;
        const float4* a0 = (const float4*)(A + i * 64 + q * 16);
        const float4* a1 = (const float4*)(A + 4096 + i * 64 + q * 16);
        const float4* a2 = (const float4*)(A + 8192 + i * 64 + q * 16);
        unsigned m16 = 0;
        #pragma unroll
        for (int j4 = 0; j4 < 4; ++j4) {
            float4 s0 = a0[j4], s1 = a1[j4], s2 = a2[j4];
            if (s0.x + s1.x + s2.x > 0.f) m16 |= 1u << (4 * j4 + 0);
            if (s0.y + s1.y + s2.y > 0.f) m16 |= 1u << (4 * j4 + 1);
            if (s0.z + s1.z + s2.z > 0.f) m16 |= 1u << (4 * j4 + 2);
            if (s0.w + s1.w + s2.w > 0.f) m16 |= 1u << (4 * j4 + 3);
        }
        part[i][q] = (unsigned short)m16;
    }
    __syncthreads();
    if (tid < 64) {
        ull m = (ull)part[tid][0] | ((ull)part[tid][1] << 16)
              | ((ull)part[tid][2] << 32) | ((ull)part[tid][3] << 48);
        mask[tid] = m;
    }
}

__global__ __launch_bounds__(256, 6) void gat_kernel(
    const float* __restrict__ x,                    // (16,64,512,64)
    const float* __restrict__ a,                    // (128,)
    const ull* __restrict__ maskbits,               // (64,)
    const unsigned short* __restrict__ Wt,          // (64,64) bf16 [v][u]
    float* __restrict__ out)                        // (16,64,512,64)
{
    // stride-72 ushort rows: b128 row-parallel access <=2-way on banks (free)
    __shared__ unsigned short XbYb[64 * 72];  // X (mm1 A) then Yb (mm2 A)
    __shared__ unsigned short WtPb[64 * 72];  // Wt (mm1 B^T) then P (mm2 B^T)
    __shared__ float al[128];
    __shared__ float fpart[4][64];
    __shared__ float gpart[4][64];
    __shared__ ull ml[64];

    const int tid  = threadIdx.x;
    const int b    = blockIdx.x;
    const int n    = b >> 9, t = b & 511;
    const int w    = tid >> 6, lane = tid & 63;
    const int fr   = lane & 15;        // fragment row/col
    const int hi   = lane >> 4;        // 0..3
    const int fk   = hi * 8;           // fragment k base

    // ---- stage X (fp32 -> bf16) ----
    {
        const int c = tid >> 2, q = tid & 3;
        const float* xp = x + (size_t)n * 2097152 + (size_t)c * 32768 + (size_t)t * 64 + q * 16;
        float4 v0 = ((const float4*)xp)[0];
        float4 v1 = ((const float4*)xp)[1];
        float4 v2 = ((const float4*)xp)[2];
        float4 v3 = ((const float4*)xp)[3];
        union { bf16x8 v; unsigned short s[8]; } u0, u1;
        u0.s[0]=f2bf(v0.x); u0.s[1]=f2bf(v0.y); u0.s[2]=f2bf(v0.z); u0.s[3]=f2bf(v0.w);
        u0.s[4]=f2bf(v1.x); u0.s[5]=f2bf(v1.y); u0.s[6]=f2bf(v1.z); u0.s[7]=f2bf(v1.w);
        u1.s[0]=f2bf(v2.x); u1.s[1]=f2bf(v2.y); u1.s[2]=f2bf(v2.z); u1.s[3]=f2bf(v2.w);
        u1.s[4]=f2bf(v3.x); u1.s[5]=f2bf(v3.y); u1.s[6]=f2bf(v3.z); u1.s[7]=f2bf(v3.w);
        *(bf16x8*)&XbYb[c * 72 + q * 16]     = u0.v;
        *(bf16x8*)&XbYb[c * 72 + q * 16 + 8] = u1.v;
    }
    // ---- stage Wt (prepped bf16): 2 coalesced b128 copies per thread ----
    #pragma unroll
    for (int p = 0; p < 2; ++p) {
        const int r  = (tid >> 3) + 32 * p;
        const int cc = (tid & 7) * 8;
        *(bf16x8*)&WtPb[r * 72 + cc] = *(const bf16x8*)&Wt[r * 64 + cc];
    }
    if (tid < 128) al[tid] = a[tid];
    if (tid >= 192) ml[tid - 192] = maskbits[tid - 192];
    __syncthreads();

    // ---- mm1: Y = X @ W; epilogue: Yb (bf16) + f/g partials from acc ----
    {
        f32x4 acc[4] = {{0,0,0,0},{0,0,0,0},{0,0,0,0},{0,0,0,0}};
        #pragma unroll
        for (int kc = 0; kc < 2; ++kc) {
            bf16x8 af = *(const bf16x8*)&XbYb[(16 * w + fr) * 72 + 32 * kc + fk];
            #pragma unroll
            for (int cb = 0; cb < 4; ++cb) {
                bf16x8 bfr = *(const bf16x8*)&WtPb[(16 * cb + fr) * 72 + 32 * kc + fk];
                acc[cb] = __builtin_amdgcn_mfma_f32_16x16x32_bf16(af, bfr, acc[cb], 0, 0, 0);
            }
        }
        float a1r[4], a2r[4];
        #pragma unroll
        for (int r = 0; r < 4; ++r) {
            a1r[r] = al[16 * w + 4 * hi + r];
            a2r[r] = al[64 + 16 * w + 4 * hi + r];
        }
        #pragma unroll
        for (int cb = 0; cb < 4; ++cb) {
            #pragma unroll
            for (int r = 0; r < 4; ++r)
                XbYb[(16 * w + 4 * hi + r) * 72 + 16 * cb + fr] = f2bf(acc[cb][r]);
            float F = acc[cb][0]*a1r[0] + acc[cb][1]*a1r[1] + acc[cb][2]*a1r[2] + acc[cb][3]*a1r[3];
            float G = acc[cb][0]*a2r[0] + acc[cb][1]*a2r[1] + acc[cb][2]*a2r[2] + acc[cb][3]*a2r[3];
            F += __shfl_xor(F, 16, 64); F += __shfl_xor(F, 32, 64);
            G += __shfl_xor(G, 16, 64); G += __shfl_xor(G, 32, 64);
            if (lane < 16) {
                fpart[w][16 * cb + lane] = F;
                gpart[w][16 * cb + lane] = G;
            }
        }
    }
    __syncthreads();

    // ---- unnormalized masked exp(lrelu(f_i+g_j)) -> P (bf16), rows i=4k+w ----
    {
        const float gj = (gpart[0][lane] + gpart[1][lane]) + (gpart[2][lane] + gpart[3][lane]);
        #pragma unroll 4
        for (int k = 0; k < 16; ++k) {
            const int i = 4 * k + w;
            const ull mi = ml[i];
            const float fi = (fpart[0][i] + fpart[1][i]) + (fpart[2][i] + fpart[3][i]);
            const float s0 = fi + gj;
            const float e  = fmaxf(s0, ALPHA * s0);
            float p;
            if (mi == 0ull) p = 1.0f;
            else            p = ((mi >> lane) & 1ull) ? __expf(e) : 0.0f;
            WtPb[i * 72 + lane] = f2bf(p);
        }
    }
    __syncthreads();

    // ---- mm2: out[c,v] = (sum_j Yb[c,j]*P[v,j]) * rcp(S_v); S via ones-MFMA ----
    {
        f32x4 acc2[4] = {{0,0,0,0},{0,0,0,0},{0,0,0,0},{0,0,0,0}};
        f32x4 accS[4] = {{0,0,0,0},{0,0,0,0},{0,0,0,0},{0,0,0,0}};
        union { bf16x8 v; unsigned short s[8]; } ones;
        #pragma unroll
        for (int j = 0; j < 8; ++j) ones.s[j] = 0x3f80;   // bf16 1.0
        #pragma unroll
        for (int kc = 0; kc < 2; ++kc) {
            bf16x8 af = *(const bf16x8*)&XbYb[(16 * w + fr) * 72 + 32 * kc + fk];
            #pragma unroll
            for (int cb = 0; cb < 4; ++cb) {
                bf16x8 bfr = *(const bf16x8*)&WtPb[(16 * cb + fr) * 72 + 32 * kc + fk];
                acc2[cb] = __builtin_amdgcn_mfma_f32_16x16x32_bf16(af, bfr, acc2[cb], 0, 0, 0);
                accS[cb] = __builtin_amdgcn_mfma_f32_16x16x32_bf16(ones.v, bfr, accS[cb], 0, 0, 0);
            }
        }
        float* op = out + (size_t)n * 2097152 + (size_t)t * 64;
        #pragma unroll
        for (int cb = 0; cb < 4; ++cb) {
            const float rs  = __builtin_amdgcn_rcpf(accS[cb][0]);
            const int   col = 16 * cb + fr;
            #pragma unroll
            for (int r = 0; r < 4; ++r) {
                const int row = 16 * w + 4 * hi + r;
                op[(size_t)row * 32768 + col] = acc2[cb][r] * rs;
            }
        }
    }
}

extern "C" void kernel_launch(void* const* d_in, const int* in_sizes, int n_in,
                              void* d_out, int out_size, void* d_ws, size_t ws_size,
                              hipStream_t stream) {
    const float* x = (const float*)d_in[0];
    const float* A = (const float*)d_in[1];
    const float* W = (const float*)d_in[2];
    const float* a = (const float*)d_in[3];
    float* out = (float*)d_out;
    unsigned short* Wt = (unsigned short*)d_ws;     // 8192 B
    ull* mask = (ull*)((char*)d_ws + 8192);         // 512 B

    prep_kernel<<<1, 256, 0, stream>>>(A, W, Wt, mask);
    gat_kernel<<<16 * 512, 256, 0, stream>>>(x, a, mask, Wt, out);
}